// Round 1
// baseline (9493.255 us; speedup 1.0000x reference)
//
#include <hip/hip_runtime.h>
#include <hip/hip_bf16.h>

#define NN 100000
#define EE 1600000
#define GG 100

__device__ __forceinline__ float silu_f(float x) {
    return x / (1.f + __expf(-x));
}

// rel_dist per edge, computed once (coors never change across layers)
__global__ void k_rd(const float* __restrict__ pos, const int* __restrict__ ei,
                     float* __restrict__ rd) {
    int e = blockIdx.x * 256 + threadIdx.x;
    if (e >= EE) return;
    int j = ei[e];        // row 0 = source j
    int i = ei[EE + e];   // row 1 = dest   i
    float dx = pos[2 * j] - pos[2 * i];
    float dy = pos[2 * j + 1] - pos[2 * i + 1];
    rd[e] = dx * dx + dy * dy;
}

// per-node partial first-GEMM: u[n] = feats[n] @ W1[0:FI], v[n] = feats[n] @ W1[FI:2FI]
template<int FI, int DH>
__global__ void k_uv(const float* __restrict__ feats, const float* __restrict__ W1,
                     float* __restrict__ u, float* __restrict__ v) {
    int idx = blockIdx.x * 256 + threadIdx.x;
    if (idx >= NN * DH) return;
    int n = idx / DH;
    int c = idx - n * DH;
    const float* f = feats + (size_t)n * FI;
    float su = 0.f, sv = 0.f;
#pragma unroll
    for (int k = 0; k < FI; k++) {
        float fk = f[k];
        su += fk * W1[k * DH + c];
        sv += fk * W1[(FI + k) * DH + c];
    }
    u[(size_t)n * DH + c] = su;
    v[(size_t)n * DH + c] = sv;
}

// edge kernel: h1 = silu(u[i]+v[j]+ea*A+rd*B+b1); m_ij = silu(h1@W2+b2); atomic scatter to m_i[i]
template<int FI, int DH>
__global__ void __launch_bounds__(256)
k_edge(const float* __restrict__ u, const float* __restrict__ v,
       const int* __restrict__ ei, const float* __restrict__ ea,
       const float* __restrict__ rd,
       const float* __restrict__ eW1, const float* __restrict__ eb1,
       const float* __restrict__ eW2, const float* __restrict__ eb2,
       float* __restrict__ mi) {
    int e = blockIdx.x * 256 + threadIdx.x;
    if (e >= EE) return;
    int j = ei[e];
    int i = ei[EE + e];
    float eav = ea[e];
    float rdv = rd[e];
    const float4* up  = (const float4*)(u + (size_t)i * DH);
    const float4* vp  = (const float4*)(v + (size_t)j * DH);
    const float4* A4  = (const float4*)(eW1 + (size_t)(2 * FI) * DH);
    const float4* B4  = (const float4*)(eW1 + (size_t)(2 * FI + 1) * DH);
    const float4* b14 = (const float4*)eb1;

    float acc[32];
#pragma unroll
    for (int m = 0; m < 32; m++) acc[m] = eb2[m];

    for (int c4 = 0; c4 < DH / 4; c4++) {
        float4 uc = up[c4];
        float4 vc = vp[c4];
        float4 a  = A4[c4];
        float4 b  = B4[c4];
        float4 bb = b14[c4];
        float t0 = silu_f(uc.x + vc.x + eav * a.x + rdv * b.x + bb.x);
        float t1 = silu_f(uc.y + vc.y + eav * a.y + rdv * b.y + bb.y);
        float t2 = silu_f(uc.z + vc.z + eav * a.z + rdv * b.z + bb.z);
        float t3 = silu_f(uc.w + vc.w + eav * a.w + rdv * b.w + bb.w);
        const float* w0 = eW2 + (size_t)(c4 * 4 + 0) * 32;
        const float* w1 = eW2 + (size_t)(c4 * 4 + 1) * 32;
        const float* w2 = eW2 + (size_t)(c4 * 4 + 2) * 32;
        const float* w3 = eW2 + (size_t)(c4 * 4 + 3) * 32;
#pragma unroll
        for (int m = 0; m < 32; m++) {
            acc[m] += t0 * w0[m] + t1 * w1[m] + t2 * w2[m] + t3 * w3[m];
        }
    }
    float* mrow = mi + (size_t)i * 32;
#pragma unroll
    for (int m = 0; m < 32; m++) {
        atomicAdd(mrow + m, silu_f(acc[m]));
    }
}

// node MLP stage 1: g = silu([feats, m_i] @ nW1 + nb1)
template<int FI>
__global__ void k_node1(const float* __restrict__ feats, const float* __restrict__ mi,
                        const float* __restrict__ nW1, const float* __restrict__ nb1,
                        float* __restrict__ g) {
    int idx = blockIdx.x * 256 + threadIdx.x;
    if (idx >= NN * 64) return;
    int n = idx >> 6;
    int c = idx & 63;
    float s = nb1[c];
    const float* f = feats + (size_t)n * FI;
#pragma unroll
    for (int k = 0; k < FI; k++) s += f[k] * nW1[k * 64 + c];
    const float* mrow = mi + (size_t)n * 32;
#pragma unroll
    for (int k = 0; k < 32; k++) s += mrow[k] * nW1[(FI + k) * 64 + c];
    g[(size_t)n * 64 + c] = silu_f(s);
}

// node MLP stage 2: feats_out = g @ nW2 + nb2  (no activation)
__global__ void k_node2(const float* __restrict__ g, const float* __restrict__ nW2,
                        const float* __restrict__ nb2, float* __restrict__ fout) {
    int idx = blockIdx.x * 256 + threadIdx.x;
    if (idx >= NN * 32) return;
    int n = idx >> 5;
    int m = idx & 31;
    float s = nb2[m];
    const float* gr = g + (size_t)n * 64;
#pragma unroll
    for (int c = 0; c < 64; c++) s += gr[c] * nW2[c * 32 + m];
    fout[(size_t)n * 32 + m] = s;
}

// per-graph mean pool + final linear. One block per graph; batch is sorted.
__global__ void k_pool(const float* __restrict__ feats, const int* __restrict__ batch,
                       const float* __restrict__ linW, const float* __restrict__ linb,
                       float* __restrict__ out) {
    int g = blockIdx.x;
    __shared__ int s_lo, s_hi;
    if (threadIdx.x == 0) {
        int lo = 0, hi = NN;
        while (lo < hi) { int mid = (lo + hi) >> 1; if (batch[mid] < g) lo = mid + 1; else hi = mid; }
        s_lo = lo;
    }
    if (threadIdx.x == 1) {
        int lo = 0, hi = NN;
        while (lo < hi) { int mid = (lo + hi) >> 1; if (batch[mid] < g + 1) lo = mid + 1; else hi = mid; }
        s_hi = lo;
    }
    __syncthreads();
    int lo = s_lo, hi = s_hi;
    int m = threadIdx.x & 31;
    int r = threadIdx.x >> 5;   // 8 rows
    float s = 0.f;
    for (int n = lo + r; n < hi; n += 8) s += feats[(size_t)n * 32 + m];
    __shared__ float sm[8][32];
    sm[r][m] = s;
    __syncthreads();
    if (threadIdx.x == 0) {
        float cntf = (float)((hi - lo) > 0 ? (hi - lo) : 1);
        float tot = 0.f;
        for (int mm = 0; mm < 32; mm++) {
            float colsum = 0.f;
            for (int rr = 0; rr < 8; rr++) colsum += sm[rr][mm];
            tot += (colsum / cntf) * linW[mm];
        }
        out[g] = tot + linb[0];
    }
}

extern "C" void kernel_launch(void* const* d_in, const int* in_sizes, int n_in,
                              void* d_out, int out_size, void* d_ws, size_t ws_size,
                              hipStream_t stream) {
    const float* x    = (const float*)d_in[0];
    const float* pos  = (const float*)d_in[1];
    const int*   ei   = (const int*)d_in[2];
    const float* ea   = (const float*)d_in[3];
    const int*   bat  = (const int*)d_in[4];
    const float* W[24];
    for (int k = 0; k < 24; k++) W[k] = (const float*)d_in[5 + k];
    const float* linW = (const float*)d_in[29];
    const float* linb = (const float*)d_in[30];
    float* out = (float*)d_out;

    // workspace layout (floats): rd | u | v | mi | fA | fB  (g aliases u)
    float* p  = (float*)d_ws;
    float* rd = p; p += EE;
    float* u  = p; p += (size_t)NN * 132;
    float* v  = p; p += (size_t)NN * 132;
    float* mi = p; p += (size_t)NN * 32;
    float* fA = p; p += (size_t)NN * 32;
    float* fB = p; p += (size_t)NN * 32;
    float* g  = u;  // u is dead once k_edge finishes; reuse for node-hidden

    k_rd<<<(EE + 255) / 256, 256, 0, stream>>>(pos, ei, rd);

    // ---- layer 1: FI=2, EIN=6, DH=12 ----
    k_uv<2, 12><<<(NN * 12 + 255) / 256, 256, 0, stream>>>(x, W[0], u, v);
    hipMemsetAsync(mi, 0, (size_t)NN * 32 * 4, stream);
    k_edge<2, 12><<<EE / 256, 256, 0, stream>>>(u, v, ei, ea, rd, W[0], W[1], W[2], W[3], mi);
    k_node1<2><<<(NN * 64) / 256, 256, 0, stream>>>(x, mi, W[4], W[5], g);
    k_node2<<<(NN * 32) / 256, 256, 0, stream>>>(g, W[6], W[7], fA);

    // ---- layer 2: FI=32, EIN=66, DH=132 ----
    k_uv<32, 132><<<(NN * 132 + 255) / 256, 256, 0, stream>>>(fA, W[8], u, v);
    hipMemsetAsync(mi, 0, (size_t)NN * 32 * 4, stream);
    k_edge<32, 132><<<EE / 256, 256, 0, stream>>>(u, v, ei, ea, rd, W[8], W[9], W[10], W[11], mi);
    k_node1<32><<<(NN * 64) / 256, 256, 0, stream>>>(fA, mi, W[12], W[13], g);
    k_node2<<<(NN * 32) / 256, 256, 0, stream>>>(g, W[14], W[15], fB);

    // ---- layer 3 ----
    k_uv<32, 132><<<(NN * 132 + 255) / 256, 256, 0, stream>>>(fB, W[16], u, v);
    hipMemsetAsync(mi, 0, (size_t)NN * 32 * 4, stream);
    k_edge<32, 132><<<EE / 256, 256, 0, stream>>>(u, v, ei, ea, rd, W[16], W[17], W[18], W[19], mi);
    k_node1<32><<<(NN * 64) / 256, 256, 0, stream>>>(fB, mi, W[20], W[21], g);
    k_node2<<<(NN * 32) / 256, 256, 0, stream>>>(g, W[22], W[23], fA);

    k_pool<<<GG, 256, 0, stream>>>(fA, bat, linW, linb, out);
}

// Round 5
// 2293.569 us; speedup vs baseline: 4.1391x; 4.1391x over previous
//
#include <hip/hip_runtime.h>
#include <hip/hip_bf16.h>

#define NN 100000
#define EE 1600000
#define GG 100

__device__ __forceinline__ float silu_f(float x) {
    return x / (1.f + __expf(-x));
}

// ---------- CSR build (once per call; topology static across layers) ----------

__global__ void k_hist(const int* __restrict__ ei, int* __restrict__ cnt) {
    int e = blockIdx.x * 256 + threadIdx.x;
    if (e >= EE) return;
    atomicAdd(&cnt[ei[EE + e]], 1);   // dest node i
}

__global__ void __launch_bounds__(1024) k_scan(const int* __restrict__ cnt,
                                               int* __restrict__ rowptr,
                                               int* __restrict__ head) {
    __shared__ int sdata[1024];
    int t = threadIdx.x;
    const int chunk = (NN + 1023) / 1024;
    int lo = t * chunk; if (lo > NN) lo = NN;
    int hi = lo + chunk; if (hi > NN) hi = NN;
    int s = 0;
    for (int n = lo; n < hi; n++) s += cnt[n];
    sdata[t] = s;
    __syncthreads();
    for (int off = 1; off < 1024; off <<= 1) {
        int val = (t >= off) ? sdata[t - off] : 0;
        __syncthreads();
        sdata[t] += val;
        __syncthreads();
    }
    int run = sdata[t] - s;  // exclusive prefix of this chunk
    for (int n = lo; n < hi; n++) {
        rowptr[n] = run; head[n] = run; run += cnt[n];
    }
    if (t == 0) rowptr[NN] = EE;
}

// packed dest-sorted edge record: {j, i, ea, rd}
__global__ void k_scatter(const int* __restrict__ ei, const float* __restrict__ ea,
                          const float* __restrict__ pos, int* __restrict__ head,
                          float4* __restrict__ recs) {
    int e = blockIdx.x * 256 + threadIdx.x;
    if (e >= EE) return;
    int j = ei[e];
    int i = ei[EE + e];
    float dx = pos[2 * j] - pos[2 * i];
    float dy = pos[2 * j + 1] - pos[2 * i + 1];
    int p = atomicAdd(&head[i], 1);
    float4 r;
    r.x = __int_as_float(j);
    r.y = __int_as_float(i);
    r.z = ea[e];
    r.w = dx * dx + dy * dy;
    recs[p] = r;
}

// ---------- per-node partial first-GEMM (bf16 out): u=feats@W1[0:FI], v=feats@W1[FI:2FI] ----------
template<int FI, int DH>
__global__ void k_uv(const float* __restrict__ feats, const float* __restrict__ W1,
                     __hip_bfloat16* __restrict__ u, __hip_bfloat16* __restrict__ v) {
    int idx = blockIdx.x * 256 + threadIdx.x;
    if (idx >= NN * DH) return;
    int n = idx / DH;
    int c = idx - n * DH;
    const float* f = feats + (size_t)n * FI;
    float su = 0.f, sv = 0.f;
#pragma unroll
    for (int k = 0; k < FI; k++) {
        float fk = f[k];
        su += fk * W1[k * DH + c];
        sv += fk * W1[(FI + k) * DH + c];
    }
    u[(size_t)n * DH + c] = __float2bfloat16(su);
    v[(size_t)n * DH + c] = __float2bfloat16(sv);
}

// ---------- fused edge MLP + wave-segmented aggregation (edges dest-sorted) ----------
// grid covers EE exactly (EE % 256 == 0) — all 64 lanes active for shuffles.
template<int FI, int DH>
__global__ void __launch_bounds__(256)
k_edge_agg(const __hip_bfloat16* __restrict__ u, const __hip_bfloat16* __restrict__ v,
           const float4* __restrict__ recs,
           const float* __restrict__ eW1, const float* __restrict__ eb1,
           const float* __restrict__ eW2, const float* __restrict__ eb2,
           float* __restrict__ mi) {
    int t = blockIdx.x * 256 + threadIdx.x;
    float4 r = recs[t];
    int j = __float_as_int(r.x);
    int i = __float_as_int(r.y);
    float eav = r.z;
    float rdv = r.w;
    const uint2* up = (const uint2*)(u + (size_t)i * DH);   // 4 bf16 per uint2
    const uint2* vp = (const uint2*)(v + (size_t)j * DH);
    const float4* A4  = (const float4*)(eW1 + (size_t)(2 * FI) * DH);
    const float4* B4  = (const float4*)(eW1 + (size_t)(2 * FI + 1) * DH);
    const float4* b14 = (const float4*)eb1;

    float acc[32];
#pragma unroll
    for (int m = 0; m < 32; m++) acc[m] = eb2[m];

    for (int c4 = 0; c4 < DH / 4; c4++) {
        uint2 uu = up[c4];
        uint2 vv = vp[c4];
        float4 a  = A4[c4];
        float4 b  = B4[c4];
        float4 bb = b14[c4];
        float u0 = __uint_as_float(uu.x << 16);
        float u1 = __uint_as_float(uu.x & 0xffff0000u);
        float u2 = __uint_as_float(uu.y << 16);
        float u3 = __uint_as_float(uu.y & 0xffff0000u);
        float v0 = __uint_as_float(vv.x << 16);
        float v1 = __uint_as_float(vv.x & 0xffff0000u);
        float v2 = __uint_as_float(vv.y << 16);
        float v3 = __uint_as_float(vv.y & 0xffff0000u);
        float t0 = silu_f(u0 + v0 + eav * a.x + rdv * b.x + bb.x);
        float t1 = silu_f(u1 + v1 + eav * a.y + rdv * b.y + bb.y);
        float t2 = silu_f(u2 + v2 + eav * a.z + rdv * b.z + bb.z);
        float t3 = silu_f(u3 + v3 + eav * a.w + rdv * b.w + bb.w);
        const float* w0 = eW2 + (size_t)(c4 * 4 + 0) * 32;
        const float* w1 = eW2 + (size_t)(c4 * 4 + 1) * 32;
        const float* w2 = eW2 + (size_t)(c4 * 4 + 2) * 32;
        const float* w3 = eW2 + (size_t)(c4 * 4 + 3) * 32;
#pragma unroll
        for (int m = 0; m < 32; m++) {
            acc[m] += t0 * w0[m] + t1 * w1[m] + t2 * w2[m] + t3 * w3[m];
        }
    }
#pragma unroll
    for (int m = 0; m < 32; m++) acc[m] = silu_f(acc[m]);   // m_ij

    // ---- wave-level segmented suffix-sum over contiguous equal-i runs ----
    int lane = threadIdx.x & 63;
#pragma unroll
    for (int d = 1; d < 64; d <<= 1) {
        int oi = __shfl_down(i, d);
        bool take = (lane + d < 64) && (oi == i);
#pragma unroll
        for (int m = 0; m < 32; m++) {
            float ov = __shfl_down(acc[m], d);
            if (take) acc[m] += ov;
        }
    }
    int previ = __shfl_up(i, 1);
    int ilast = __shfl(i, 63);
    bool leader = (lane == 0) || (previ != i);
    if (leader) {
        float* row = mi + (size_t)i * 32;
        bool interior = (lane != 0) && (ilast != i);  // node's edges fully inside this wave
        if (interior) {
            float4* row4 = (float4*)row;
#pragma unroll
            for (int q = 0; q < 8; q++)
                row4[q] = make_float4(acc[4 * q], acc[4 * q + 1], acc[4 * q + 2], acc[4 * q + 3]);
        } else {
#pragma unroll
            for (int m = 0; m < 32; m++) atomicAdd(row + m, acc[m]);
        }
    }
}

// ---------- node MLP ----------
template<int FI>
__global__ void k_node1(const float* __restrict__ feats, const float* __restrict__ mi,
                        const float* __restrict__ nW1, const float* __restrict__ nb1,
                        float* __restrict__ g) {
    int idx = blockIdx.x * 256 + threadIdx.x;
    if (idx >= NN * 64) return;
    int n = idx >> 6;
    int c = idx & 63;
    float s = nb1[c];
    const float* f = feats + (size_t)n * FI;
#pragma unroll
    for (int k = 0; k < FI; k++) s += f[k] * nW1[k * 64 + c];
    const float* mrow = mi + (size_t)n * 32;
#pragma unroll
    for (int k = 0; k < 32; k++) s += mrow[k] * nW1[(FI + k) * 64 + c];
    g[(size_t)n * 64 + c] = silu_f(s);
}

__global__ void k_node2(const float* __restrict__ g, const float* __restrict__ nW2,
                        const float* __restrict__ nb2, float* __restrict__ fout) {
    int idx = blockIdx.x * 256 + threadIdx.x;
    if (idx >= NN * 32) return;
    int n = idx >> 5;
    int m = idx & 31;
    float s = nb2[m];
    const float* gr = g + (size_t)n * 64;
#pragma unroll
    for (int c = 0; c < 64; c++) s += gr[c] * nW2[c * 32 + m];
    fout[(size_t)n * 32 + m] = s;
}

// ---------- per-graph mean pool + final linear ----------
__global__ void k_pool(const float* __restrict__ feats, const int* __restrict__ batch,
                       const float* __restrict__ linW, const float* __restrict__ linb,
                       float* __restrict__ out) {
    int g = blockIdx.x;
    __shared__ int s_lo, s_hi;
    if (threadIdx.x == 0) {
        int lo = 0, hi = NN;
        while (lo < hi) { int mid = (lo + hi) >> 1; if (batch[mid] < g) lo = mid + 1; else hi = mid; }
        s_lo = lo;
    }
    if (threadIdx.x == 1) {
        int lo = 0, hi = NN;
        while (lo < hi) { int mid = (lo + hi) >> 1; if (batch[mid] < g + 1) lo = mid + 1; else hi = mid; }
        s_hi = lo;
    }
    __syncthreads();
    int lo = s_lo, hi = s_hi;
    int m = threadIdx.x & 31;
    int r = threadIdx.x >> 5;   // 8 rows
    float s = 0.f;
    for (int n = lo + r; n < hi; n += 8) s += feats[(size_t)n * 32 + m];
    __shared__ float sm[8][32];
    sm[r][m] = s;
    __syncthreads();
    if (threadIdx.x == 0) {
        float cntf = (float)((hi - lo) > 0 ? (hi - lo) : 1);
        float tot = 0.f;
        for (int mm = 0; mm < 32; mm++) {
            float colsum = 0.f;
            for (int rr = 0; rr < 8; rr++) colsum += sm[rr][mm];
            tot += (colsum / cntf) * linW[mm];
        }
        out[g] = tot + linb[0];
    }
}

extern "C" void kernel_launch(void* const* d_in, const int* in_sizes, int n_in,
                              void* d_out, int out_size, void* d_ws, size_t ws_size,
                              hipStream_t stream) {
    const float* x    = (const float*)d_in[0];
    const float* pos  = (const float*)d_in[1];
    const int*   ei   = (const int*)d_in[2];
    const float* ea   = (const float*)d_in[3];
    const int*   bat  = (const int*)d_in[4];
    const float* W[24];
    for (int k = 0; k < 24; k++) W[k] = (const float*)d_in[5 + k];
    const float* linW = (const float*)d_in[29];
    const float* linb = (const float*)d_in[30];
    float* out = (float*)d_out;

    // workspace layout — total ~105 MB (proven-safe: 150 MB worked in round 1)
    char* p = (char*)d_ws;
    float4*          recs = (float4*)p;          p += (size_t)EE * 16;            // 25.6 MB
    __hip_bfloat16*  u    = (__hip_bfloat16*)p;  p += (size_t)NN * 132 * 2;       // 26.4 MB
    __hip_bfloat16*  v    = (__hip_bfloat16*)p;  p += (size_t)NN * 132 * 2;       // 26.4 MB
    float*           mi   = (float*)p;           p += (size_t)NN * 32 * 4;        // 12.8 MB
    float*           f    = (float*)p;           p += (size_t)NN * 32 * 4;        // 12.8 MB
    int*             cnt  = (int*)p;             p += (size_t)NN * 4;
    int*             rowptr = (int*)p;           p += (size_t)(NN + 4) * 4;
    int*             head = (int*)p;             p += (size_t)NN * 4;
    float*           g    = (float*)u;   // u/v dead after k_edge_agg; 52.8 MB region, g needs 25.6 MB

    // ---- CSR build (once) ----
    hipMemsetAsync(cnt, 0, (size_t)NN * 4, stream);
    k_hist<<<EE / 256, 256, 0, stream>>>(ei, cnt);
    k_scan<<<1, 1024, 0, stream>>>(cnt, rowptr, head);
    k_scatter<<<EE / 256, 256, 0, stream>>>(ei, ea, pos, head, recs);

    // ---- layer 1: FI=2, DH=12 ----
    k_uv<2, 12><<<(NN * 12 + 255) / 256, 256, 0, stream>>>(x, W[0], u, v);
    hipMemsetAsync(mi, 0, (size_t)NN * 32 * 4, stream);
    k_edge_agg<2, 12><<<EE / 256, 256, 0, stream>>>(u, v, recs, W[0], W[1], W[2], W[3], mi);
    k_node1<2><<<(NN * 64) / 256, 256, 0, stream>>>(x, mi, W[4], W[5], g);
    k_node2<<<(NN * 32) / 256, 256, 0, stream>>>(g, W[6], W[7], f);

    // ---- layer 2: FI=32, DH=132 ----
    k_uv<32, 132><<<(NN * 132 + 255) / 256, 256, 0, stream>>>(f, W[8], u, v);
    hipMemsetAsync(mi, 0, (size_t)NN * 32 * 4, stream);
    k_edge_agg<32, 132><<<EE / 256, 256, 0, stream>>>(u, v, recs, W[8], W[9], W[10], W[11], mi);
    k_node1<32><<<(NN * 64) / 256, 256, 0, stream>>>(f, mi, W[12], W[13], g);
    k_node2<<<(NN * 32) / 256, 256, 0, stream>>>(g, W[14], W[15], f);

    // ---- layer 3 ----
    k_uv<32, 132><<<(NN * 132 + 255) / 256, 256, 0, stream>>>(f, W[16], u, v);
    hipMemsetAsync(mi, 0, (size_t)NN * 32 * 4, stream);
    k_edge_agg<32, 132><<<EE / 256, 256, 0, stream>>>(u, v, recs, W[16], W[17], W[18], W[19], mi);
    k_node1<32><<<(NN * 64) / 256, 256, 0, stream>>>(f, mi, W[20], W[21], g);
    k_node2<<<(NN * 32) / 256, 256, 0, stream>>>(g, W[22], W[23], f);

    k_pool<<<GG, 256, 0, stream>>>(f, bat, linW, linb, out);
}

// Round 7
// 2203.030 us; speedup vs baseline: 4.3092x; 1.0411x over previous
//
#include <hip/hip_runtime.h>
#include <hip/hip_bf16.h>

#define NN 100000
#define EE 1600000
#define GG 100

typedef __fp16 h2 __attribute__((ext_vector_type(2)));

#if __has_builtin(__builtin_amdgcn_fdot2)
#define FDOT2(a, b, c) __builtin_amdgcn_fdot2((a), (b), (c), false)
#else
__device__ __forceinline__ float FDOT2(h2 a, h2 b, float c) {
    return (float)a.x * (float)b.x + (float)a.y * (float)b.y + c;
}
#endif

__device__ __forceinline__ float silu_f(float x) {
    return x / (1.f + __expf(-x));
}

__device__ __forceinline__ float2 h2f2(unsigned int w) {
    h2 h = __builtin_bit_cast(h2, w);
    return make_float2((float)h.x, (float)h.y);
}

// ---------- CSR build (once per call; topology static across layers) ----------

__global__ void k_hist(const int* __restrict__ ei, int* __restrict__ cnt) {
    int e = blockIdx.x * 256 + threadIdx.x;
    if (e >= EE) return;
    atomicAdd(&cnt[ei[EE + e]], 1);   // dest node i
}

__global__ void __launch_bounds__(1024) k_scan(const int* __restrict__ cnt,
                                               int* __restrict__ rowptr,
                                               int* __restrict__ head) {
    __shared__ int sdata[1024];
    int t = threadIdx.x;
    const int chunk = (NN + 1023) / 1024;
    int lo = t * chunk; if (lo > NN) lo = NN;
    int hi = lo + chunk; if (hi > NN) hi = NN;
    int s = 0;
    for (int n = lo; n < hi; n++) s += cnt[n];
    sdata[t] = s;
    __syncthreads();
    for (int off = 1; off < 1024; off <<= 1) {
        int val = (t >= off) ? sdata[t - off] : 0;
        __syncthreads();
        sdata[t] += val;
        __syncthreads();
    }
    int run = sdata[t] - s;  // exclusive prefix of this chunk
    for (int n = lo; n < hi; n++) {
        rowptr[n] = run; head[n] = run; run += cnt[n];
    }
    if (t == 0) rowptr[NN] = EE;
}

// packed dest-sorted edge record: {j, i, ea, rd}
__global__ void k_scatter(const int* __restrict__ ei, const float* __restrict__ ea,
                          const float* __restrict__ pos, int* __restrict__ head,
                          float4* __restrict__ recs) {
    int e = blockIdx.x * 256 + threadIdx.x;
    if (e >= EE) return;
    int j = ei[e];
    int i = ei[EE + e];
    float dx = pos[2 * j] - pos[2 * i];
    float dy = pos[2 * j + 1] - pos[2 * i + 1];
    int p = atomicAdd(&head[i], 1);
    float4 r;
    r.x = __int_as_float(j);
    r.y = __int_as_float(i);
    r.z = ea[e];
    r.w = dx * dx + dy * dy;
    recs[p] = r;
}

// ---------- pack eW2 (DHx32 f32) into fp16 pairs: w2pk[p*32+m] = {W2[2p][m], W2[2p+1][m]} ----------
template<int DH>
__global__ void k_packw2(const float* __restrict__ W2, h2* __restrict__ dst) {
    int idx = blockIdx.x * 256 + threadIdx.x;
    if (idx >= (DH / 2) * 32) return;
    int p = idx >> 5;
    int m = idx & 31;
    dst[idx] = __builtin_amdgcn_cvt_pkrtz(W2[(2 * p) * 32 + m], W2[(2 * p + 1) * 32 + m]);
}

// ---------- per-node partial first-GEMM (fp16 out): u=feats@W1[0:FI], v=feats@W1[FI:2FI] ----------
template<int FI, int DH>
__global__ void k_uv(const float* __restrict__ feats, const float* __restrict__ W1,
                     __fp16* __restrict__ u, __fp16* __restrict__ v) {
    int idx = blockIdx.x * 256 + threadIdx.x;
    if (idx >= NN * DH) return;
    int n = idx / DH;
    int c = idx - n * DH;
    const float* f = feats + (size_t)n * FI;
    float su = 0.f, sv = 0.f;
#pragma unroll
    for (int k = 0; k < FI; k++) {
        float fk = f[k];
        su += fk * W1[k * DH + c];
        sv += fk * W1[(FI + k) * DH + c];
    }
    u[(size_t)n * DH + c] = (__fp16)su;
    v[(size_t)n * DH + c] = (__fp16)sv;
}

// ---------- fused edge MLP + wave-segmented aggregation (edges dest-sorted) ----------
// grid covers EE exactly (EE % 256 == 0) — all 64 lanes active for shuffles.
template<int FI, int DH>
__global__ void __launch_bounds__(256)
k_edge_agg(const __fp16* __restrict__ u, const __fp16* __restrict__ v,
           const float4* __restrict__ recs,
           const float* __restrict__ eW1, const float* __restrict__ eb1,
           const h2* __restrict__ w2pk, const float* __restrict__ eb2,
           float* __restrict__ mi) {
    int t = blockIdx.x * 256 + threadIdx.x;
    float4 r = recs[t];
    int j = __float_as_int(r.x);
    int i = __float_as_int(r.y);
    float eav = r.z;
    float rdv = r.w;
    const uint2* up = (const uint2*)(u + (size_t)i * DH);   // 4 fp16 per uint2
    const uint2* vp = (const uint2*)(v + (size_t)j * DH);
    const float4* A4  = (const float4*)(eW1 + (size_t)(2 * FI) * DH);
    const float4* B4  = (const float4*)(eW1 + (size_t)(2 * FI + 1) * DH);
    const float4* b14 = (const float4*)eb1;

    float acc[32];
#pragma unroll
    for (int m = 0; m < 32; m++) acc[m] = eb2[m];

    for (int c4 = 0; c4 < DH / 4; c4++) {
        uint2 uu = up[c4];
        uint2 vv = vp[c4];
        float4 a  = A4[c4];
        float4 b  = B4[c4];
        float4 bb = b14[c4];
        float2 u01 = h2f2(uu.x), u23 = h2f2(uu.y);
        float2 v01 = h2f2(vv.x), v23 = h2f2(vv.y);
        float t0 = silu_f(u01.x + v01.x + eav * a.x + rdv * b.x + bb.x);
        float t1 = silu_f(u01.y + v01.y + eav * a.y + rdv * b.y + bb.y);
        float t2 = silu_f(u23.x + v23.x + eav * a.z + rdv * b.z + bb.z);
        float t3 = silu_f(u23.y + v23.y + eav * a.w + rdv * b.w + bb.w);
        h2 hp0 = __builtin_amdgcn_cvt_pkrtz(t0, t1);   // pair 2*c4
        h2 hp1 = __builtin_amdgcn_cvt_pkrtz(t2, t3);   // pair 2*c4+1
        const h2* w0 = w2pk + (size_t)(2 * c4) * 32;
        const h2* w1 = w0 + 32;
#pragma unroll
        for (int m = 0; m < 32; m++) {
            acc[m] = FDOT2(hp0, w0[m], acc[m]);
            acc[m] = FDOT2(hp1, w1[m], acc[m]);
        }
    }
#pragma unroll
    for (int m = 0; m < 32; m++) acc[m] = silu_f(acc[m]);   // m_ij

    // ---- wave-level segmented suffix-sum over contiguous equal-i runs ----
    int lane = threadIdx.x & 63;
#pragma unroll
    for (int d = 1; d < 64; d <<= 1) {
        int oi = __shfl_down(i, d);
        bool take = (lane + d < 64) && (oi == i);
#pragma unroll
        for (int m = 0; m < 32; m++) {
            float ov = __shfl_down(acc[m], d);
            if (take) acc[m] += ov;
        }
    }
    int previ = __shfl_up(i, 1);
    int ilast = __shfl(i, 63);
    bool leader = (lane == 0) || (previ != i);
    if (leader) {
        float* row = mi + (size_t)i * 32;
        bool interior = (lane != 0) && (ilast != i);  // node's edges fully inside this wave
        if (interior) {
            float4* row4 = (float4*)row;
#pragma unroll
            for (int q = 0; q < 8; q++)
                row4[q] = make_float4(acc[4 * q], acc[4 * q + 1], acc[4 * q + 2], acc[4 * q + 3]);
        } else {
#pragma unroll
            for (int m = 0; m < 32; m++) atomicAdd(row + m, acc[m]);
        }
    }
}

// ---------- fused node MLP: g = silu([f, mi] @ nW1 + nb1) in LDS; fout = g @ nW2 + nb2 ----------
// block = 256 threads = 4 nodes x 64 lanes (one wave per node)
template<int FI>
__global__ void __launch_bounds__(256)
k_node(const float* __restrict__ feats, const float* __restrict__ mi,
       const float* __restrict__ nW1, const float* __restrict__ nb1,
       const float* __restrict__ nW2, const float* __restrict__ nb2,
       float* __restrict__ fout) {
    __shared__ float g_lds[4][64];
    int ln = threadIdx.x >> 6;          // local node 0..3
    int c  = threadIdx.x & 63;
    int n  = blockIdx.x * 4 + ln;       // NN % 4 == 0
    float s = nb1[c];
    const float* f = feats + (size_t)n * FI;
#pragma unroll
    for (int k = 0; k < FI; k++) s += f[k] * nW1[k * 64 + c];
    const float* mrow = mi + (size_t)n * 32;
#pragma unroll
    for (int k = 0; k < 32; k++) s += mrow[k] * nW1[(FI + k) * 64 + c];
    g_lds[ln][c] = silu_f(s);
    __syncthreads();
    if (c < 32) {
        float o = nb2[c];
        const float* gr = g_lds[ln];
#pragma unroll
        for (int k = 0; k < 64; k++) o += gr[k] * nW2[k * 32 + c];
        fout[(size_t)n * 32 + c] = o;
    }
}

// ---------- per-graph mean pool + final linear ----------
__global__ void k_pool(const float* __restrict__ feats, const int* __restrict__ batch,
                       const float* __restrict__ linW, const float* __restrict__ linb,
                       float* __restrict__ out) {
    int g = blockIdx.x;
    __shared__ int s_lo, s_hi;
    if (threadIdx.x == 0) {
        int lo = 0, hi = NN;
        while (lo < hi) { int mid = (lo + hi) >> 1; if (batch[mid] < g) lo = mid + 1; else hi = mid; }
        s_lo = lo;
    }
    if (threadIdx.x == 1) {
        int lo = 0, hi = NN;
        while (lo < hi) { int mid = (lo + hi) >> 1; if (batch[mid] < g + 1) lo = mid + 1; else hi = mid; }
        s_hi = lo;
    }
    __syncthreads();
    int lo = s_lo, hi = s_hi;
    int m = threadIdx.x & 31;
    int r = threadIdx.x >> 5;   // 8 rows
    float s = 0.f;
    for (int n = lo + r; n < hi; n += 8) s += feats[(size_t)n * 32 + m];
    __shared__ float sm[8][32];
    sm[r][m] = s;
    __syncthreads();
    if (threadIdx.x == 0) {
        float cntf = (float)((hi - lo) > 0 ? (hi - lo) : 1);
        float tot = 0.f;
        for (int mm = 0; mm < 32; mm++) {
            float colsum = 0.f;
            for (int rr = 0; rr < 8; rr++) colsum += sm[rr][mm];
            tot += (colsum / cntf) * linW[mm];
        }
        out[g] = tot + linb[0];
    }
}

extern "C" void kernel_launch(void* const* d_in, const int* in_sizes, int n_in,
                              void* d_out, int out_size, void* d_ws, size_t ws_size,
                              hipStream_t stream) {
    const float* x    = (const float*)d_in[0];
    const float* pos  = (const float*)d_in[1];
    const int*   ei   = (const int*)d_in[2];
    const float* ea   = (const float*)d_in[3];
    const int*   bat  = (const int*)d_in[4];
    const float* W[24];
    for (int k = 0; k < 24; k++) W[k] = (const float*)d_in[5 + k];
    const float* linW = (const float*)d_in[29];
    const float* linb = (const float*)d_in[30];
    float* out = (float*)d_out;

    // workspace layout — ~106 MB (150 MB proven safe in round 1)
    char* p = (char*)d_ws;
    float4*  recs = (float4*)p;         p += (size_t)EE * 16;            // 25.6 MB
    __fp16*  u    = (__fp16*)p;         p += (size_t)NN * 132 * 2;       // 26.4 MB
    __fp16*  v    = (__fp16*)p;         p += (size_t)NN * 132 * 2;       // 26.4 MB
    float*   mi   = (float*)p;          p += (size_t)NN * 32 * 4;        // 12.8 MB
    float*   f    = (float*)p;          p += (size_t)NN * 32 * 4;        // 12.8 MB
    h2*      w2p1 = (h2*)p;             p += (size_t)(6  * 32) * 4;
    h2*      w2p2 = (h2*)p;             p += (size_t)(66 * 32) * 4;
    h2*      w2p3 = (h2*)p;             p += (size_t)(66 * 32) * 4;
    int*     cnt  = (int*)p;            p += (size_t)NN * 4;
    int*     rowptr = (int*)p;          p += (size_t)(NN + 4) * 4;
    int*     head = (int*)p;            p += (size_t)NN * 4;

    // ---- CSR build + weight prepack (once) ----
    (void)hipMemsetAsync(cnt, 0, (size_t)NN * 4, stream);
    k_hist<<<EE / 256, 256, 0, stream>>>(ei, cnt);
    k_scan<<<1, 1024, 0, stream>>>(cnt, rowptr, head);
    k_scatter<<<EE / 256, 256, 0, stream>>>(ei, ea, pos, head, recs);
    k_packw2<12> <<<1, 256, 0, stream>>>(W[2],  w2p1);
    k_packw2<132><<<(66 * 32 + 255) / 256, 256, 0, stream>>>(W[10], w2p2);
    k_packw2<132><<<(66 * 32 + 255) / 256, 256, 0, stream>>>(W[18], w2p3);

    // ---- layer 1: FI=2, DH=12 ----
    k_uv<2, 12><<<(NN * 12 + 255) / 256, 256, 0, stream>>>(x, W[0], u, v);
    (void)hipMemsetAsync(mi, 0, (size_t)NN * 32 * 4, stream);
    k_edge_agg<2, 12><<<EE / 256, 256, 0, stream>>>(u, v, recs, W[0], W[1], w2p1, W[3], mi);
    k_node<2><<<NN / 4, 256, 0, stream>>>(x, mi, W[4], W[5], W[6], W[7], f);

    // ---- layer 2: FI=32, DH=132 ----
    k_uv<32, 132><<<(NN * 132 + 255) / 256, 256, 0, stream>>>(f, W[8], u, v);
    (void)hipMemsetAsync(mi, 0, (size_t)NN * 32 * 4, stream);
    k_edge_agg<32, 132><<<EE / 256, 256, 0, stream>>>(u, v, recs, W[8], W[9], w2p2, W[11], mi);
    k_node<32><<<NN / 4, 256, 0, stream>>>(f, mi, W[12], W[13], W[14], W[15], f);

    // ---- layer 3 ----
    k_uv<32, 132><<<(NN * 132 + 255) / 256, 256, 0, stream>>>(f, W[16], u, v);
    (void)hipMemsetAsync(mi, 0, (size_t)NN * 32 * 4, stream);
    k_edge_agg<32, 132><<<EE / 256, 256, 0, stream>>>(u, v, recs, W[16], W[17], w2p3, W[19], mi);
    k_node<32><<<NN / 4, 256, 0, stream>>>(f, mi, W[20], W[21], W[22], W[23], f);

    k_pool<<<GG, 256, 0, stream>>>(f, bat, linW, linb, out);
}

// Round 8
// 1911.501 us; speedup vs baseline: 4.9664x; 1.1525x over previous
//
#include <hip/hip_runtime.h>
#include <hip/hip_bf16.h>

#define NN 100000
#define EE 1600000
#define GG 100

typedef __fp16 h2 __attribute__((ext_vector_type(2)));

#if __has_builtin(__builtin_amdgcn_fdot2)
#define FDOT2(a, b, c) __builtin_amdgcn_fdot2((a), (b), (c), false)
#else
__device__ __forceinline__ float FDOT2(h2 a, h2 b, float c) {
    return (float)a.x * (float)b.x + (float)a.y * (float)b.y + c;
}
#endif

__device__ __forceinline__ float silu_f(float x) {
    return x / (1.f + __expf(-x));
}

__device__ __forceinline__ float2 h2f2(unsigned int w) {
    h2 h = __builtin_bit_cast(h2, w);
    return make_float2((float)h.x, (float)h.y);
}

// ---------- CSR build (once per call; topology static across layers) ----------

__global__ void k_hist(const int* __restrict__ ei, int* __restrict__ cnt) {
    int e = blockIdx.x * 256 + threadIdx.x;
    if (e >= EE) return;
    atomicAdd(&cnt[ei[EE + e]], 1);   // dest node i
}

__global__ void __launch_bounds__(1024) k_scan(const int* __restrict__ cnt,
                                               int* __restrict__ rowptr,
                                               int* __restrict__ head) {
    __shared__ int sdata[1024];
    int t = threadIdx.x;
    const int chunk = (NN + 1023) / 1024;
    int lo = t * chunk; if (lo > NN) lo = NN;
    int hi = lo + chunk; if (hi > NN) hi = NN;
    int s = 0;
    for (int n = lo; n < hi; n++) s += cnt[n];
    sdata[t] = s;
    __syncthreads();
    for (int off = 1; off < 1024; off <<= 1) {
        int val = (t >= off) ? sdata[t - off] : 0;
        __syncthreads();
        sdata[t] += val;
        __syncthreads();
    }
    int run = sdata[t] - s;  // exclusive prefix of this chunk
    for (int n = lo; n < hi; n++) {
        rowptr[n] = run; head[n] = run; run += cnt[n];
    }
    if (t == 0) rowptr[NN] = EE;
}

// packed dest-sorted edge record: {j, i, ea, rd}
__global__ void k_scatter(const int* __restrict__ ei, const float* __restrict__ ea,
                          const float* __restrict__ pos, int* __restrict__ head,
                          float4* __restrict__ recs) {
    int e = blockIdx.x * 256 + threadIdx.x;
    if (e >= EE) return;
    int j = ei[e];
    int i = ei[EE + e];
    float dx = pos[2 * j] - pos[2 * i];
    float dy = pos[2 * j + 1] - pos[2 * i + 1];
    int p = atomicAdd(&head[i], 1);
    float4 r;
    r.x = __int_as_float(j);
    r.y = __int_as_float(i);
    r.z = ea[e];
    r.w = dx * dx + dy * dy;
    recs[p] = r;
}

// ---------- pack eW2 (DHx32 f32) into fp16 pairs: w2pk[p*32+m] = {W2[2p][m], W2[2p+1][m]} ----------
template<int DH>
__global__ void k_packw2(const float* __restrict__ W2, h2* __restrict__ dst) {
    int idx = blockIdx.x * 256 + threadIdx.x;
    if (idx >= (DH / 2) * 32) return;
    int p = idx >> 5;
    int m = idx & 31;
    dst[idx] = __builtin_amdgcn_cvt_pkrtz(W2[(2 * p) * 32 + m], W2[(2 * p + 1) * 32 + m]);
}

// ---------- per-node partial first-GEMM for LAYER 1 only ----------
template<int FI, int DH>
__global__ void k_uv(const float* __restrict__ feats, const float* __restrict__ W1,
                     __fp16* __restrict__ u, __fp16* __restrict__ v) {
    int idx = blockIdx.x * 256 + threadIdx.x;
    if (idx >= NN * DH) return;
    int n = idx / DH;
    int c = idx - n * DH;
    const float* f = feats + (size_t)n * FI;
    float su = 0.f, sv = 0.f;
#pragma unroll
    for (int k = 0; k < FI; k++) {
        float fk = f[k];
        su += fk * W1[k * DH + c];
        sv += fk * W1[(FI + k) * DH + c];
    }
    u[(size_t)n * DH + c] = (__fp16)su;
    v[(size_t)n * DH + c] = (__fp16)sv;
}

// ---------- fused edge MLP + wave-segmented aggregation ----------
// LDS-staged weights (no per-edge weight VMEM); h1 in registers; grouped u/v loads.
template<int FI, int DH>
__global__ void __launch_bounds__(256)
k_edge_agg(const __fp16* __restrict__ u, const __fp16* __restrict__ v,
           const float4* __restrict__ recs,
           const float* __restrict__ eW1, const float* __restrict__ eb1,
           const h2* __restrict__ w2pk, const float* __restrict__ eb2,
           float* __restrict__ mi) {
    constexpr int NC4 = DH / 4;                 // uint2 chunks per row
    constexpr int NP  = DH / 2;                 // h2 pairs per row
    constexpr int GK  = (NC4 >= 11) ? 11 : NC4; // load-group size
    constexpr int NGR = NC4 / GK;               // 3 for DH=132, 1 for DH=12

    __shared__ __align__(16) float sA[DH], sB[DH], sb1[DH];
    __shared__ float sb2[32];
    __shared__ __align__(16) h2 sw2[NP * 32];

    for (int k = threadIdx.x; k < DH; k += 256) {
        sA[k]  = eW1[(2 * FI) * DH + k];
        sB[k]  = eW1[(2 * FI + 1) * DH + k];
        sb1[k] = eb1[k];
    }
    for (int k = threadIdx.x; k < NP * 32; k += 256) sw2[k] = w2pk[k];
    if (threadIdx.x < 32) sb2[threadIdx.x] = eb2[threadIdx.x];
    __syncthreads();

    int t = blockIdx.x * 256 + threadIdx.x;     // EE % 256 == 0
    float4 r = recs[t];
    int j = __float_as_int(r.x);
    int i = __float_as_int(r.y);
    float eav = r.z;
    float rdv = r.w;
    const uint2* up = (const uint2*)(u + (size_t)i * DH);
    const uint2* vp = (const uint2*)(v + (size_t)j * DH);

    // ---- h1 = silu(u_i + v_j + ea*A + rd*B + b1), kept in registers as fp16 pairs ----
    h2 hreg[NP];
#pragma unroll
    for (int g = 0; g < NGR; g++) {
        uint2 ub[GK], vb[GK];
#pragma unroll
        for (int k = 0; k < GK; k++) {
            ub[k] = up[g * GK + k];
            vb[k] = vp[g * GK + k];
        }
#pragma unroll
        for (int k = 0; k < GK; k++) {
            int c4 = g * GK + k;
            float2 u01 = h2f2(ub[k].x), u23 = h2f2(ub[k].y);
            float2 v01 = h2f2(vb[k].x), v23 = h2f2(vb[k].y);
            float4 a  = *(const float4*)&sA[c4 * 4];
            float4 b  = *(const float4*)&sB[c4 * 4];
            float4 bb = *(const float4*)&sb1[c4 * 4];
            float t0 = silu_f(u01.x + v01.x + eav * a.x + rdv * b.x + bb.x);
            float t1 = silu_f(u01.y + v01.y + eav * a.y + rdv * b.y + bb.y);
            float t2 = silu_f(u23.x + v23.x + eav * a.z + rdv * b.z + bb.z);
            float t3 = silu_f(u23.y + v23.y + eav * a.w + rdv * b.w + bb.w);
            hreg[2 * c4]     = __builtin_amdgcn_cvt_pkrtz(t0, t1);
            hreg[2 * c4 + 1] = __builtin_amdgcn_cvt_pkrtz(t2, t3);
        }
    }

    // ---- m_ij = silu(h1 @ W2 + b2): W2 from LDS (uniform b128), 4 acc chains in flight ----
    float acc[32];
#pragma unroll
    for (int m = 0; m < 32; m++) acc[m] = sb2[m];
#pragma unroll
    for (int mg = 0; mg < 8; mg++) {
#pragma unroll
        for (int p = 0; p < NP; p++) {
            uint4 W = *(const uint4*)(sw2 + p * 32 + mg * 4);
            acc[4 * mg + 0] = FDOT2(hreg[p], __builtin_bit_cast(h2, W.x), acc[4 * mg + 0]);
            acc[4 * mg + 1] = FDOT2(hreg[p], __builtin_bit_cast(h2, W.y), acc[4 * mg + 1]);
            acc[4 * mg + 2] = FDOT2(hreg[p], __builtin_bit_cast(h2, W.z), acc[4 * mg + 2]);
            acc[4 * mg + 3] = FDOT2(hreg[p], __builtin_bit_cast(h2, W.w), acc[4 * mg + 3]);
        }
    }
#pragma unroll
    for (int m = 0; m < 32; m++) acc[m] = silu_f(acc[m]);   // m_ij

    // ---- wave-level segmented suffix-sum over contiguous equal-i runs ----
    int lane = threadIdx.x & 63;
#pragma unroll
    for (int d = 1; d < 64; d <<= 1) {
        int oi = __shfl_down(i, d);
        bool take = (lane + d < 64) && (oi == i);
#pragma unroll
        for (int m = 0; m < 32; m++) {
            float ov = __shfl_down(acc[m], d);
            if (take) acc[m] += ov;
        }
    }
    int previ = __shfl_up(i, 1);
    int ilast = __shfl(i, 63);
    bool leader = (lane == 0) || (previ != i);
    if (leader) {
        float* row = mi + (size_t)i * 32;
        bool interior = (lane != 0) && (ilast != i);  // node's edges fully inside this wave
        if (interior) {
            float4* row4 = (float4*)row;
#pragma unroll
            for (int q = 0; q < 8; q++)
                row4[q] = make_float4(acc[4 * q], acc[4 * q + 1], acc[4 * q + 2], acc[4 * q + 3]);
        } else {
#pragma unroll
            for (int m = 0; m < 32; m++) atomicAdd(row + m, acc[m]);
        }
    }
}

// ---------- fused node MLP (+ next-layer u/v when NDH>0) ----------
// block = 256 threads = 4 nodes x 64 lanes (one wave per node)
template<int FI, int NDH>
__global__ void __launch_bounds__(256)
k_node(const float* __restrict__ feats, const float* __restrict__ mi,
       const float* __restrict__ nW1, const float* __restrict__ nb1,
       const float* __restrict__ nW2, const float* __restrict__ nb2,
       float* __restrict__ fout,
       const float* __restrict__ eW1n,   // next layer's eW1 (66 x NDH), or null
       __fp16* __restrict__ un, __fp16* __restrict__ vn) {
    __shared__ float g_lds[4][64];
    __shared__ float s_f[4][32];
    int ln = threadIdx.x >> 6;          // local node 0..3
    int c  = threadIdx.x & 63;
    int n  = blockIdx.x * 4 + ln;       // NN % 4 == 0
    float s = nb1[c];
    const float* f = feats + (size_t)n * FI;
#pragma unroll
    for (int k = 0; k < FI; k++) s += f[k] * nW1[k * 64 + c];
    const float* mrow = mi + (size_t)n * 32;
#pragma unroll
    for (int k = 0; k < 32; k++) s += mrow[k] * nW1[(FI + k) * 64 + c];
    g_lds[ln][c] = silu_f(s);
    __syncthreads();
    if (c < 32) {
        float o = nb2[c];
        const float* gr = g_lds[ln];
#pragma unroll
        for (int k = 0; k < 64; k++) o += gr[k] * nW2[k * 32 + c];
        fout[(size_t)n * 32 + c] = o;
        s_f[ln][c] = o;
    }
    if (NDH > 0) {
        __syncthreads();
        const float* fr = s_f[ln];
        for (int col = c; col < NDH; col += 64) {
            float su = 0.f, sv = 0.f;
#pragma unroll
            for (int k = 0; k < 32; k++) {
                float fk = fr[k];
                su += fk * eW1n[k * NDH + col];
                sv += fk * eW1n[(32 + k) * NDH + col];
            }
            un[(size_t)n * NDH + col] = (__fp16)su;
            vn[(size_t)n * NDH + col] = (__fp16)sv;
        }
    }
}

// ---------- per-graph mean pool + final linear ----------
__global__ void k_pool(const float* __restrict__ feats, const int* __restrict__ batch,
                       const float* __restrict__ linW, const float* __restrict__ linb,
                       float* __restrict__ out) {
    int g = blockIdx.x;
    __shared__ int s_lo, s_hi;
    if (threadIdx.x == 0) {
        int lo = 0, hi = NN;
        while (lo < hi) { int mid = (lo + hi) >> 1; if (batch[mid] < g) lo = mid + 1; else hi = mid; }
        s_lo = lo;
    }
    if (threadIdx.x == 1) {
        int lo = 0, hi = NN;
        while (lo < hi) { int mid = (lo + hi) >> 1; if (batch[mid] < g + 1) lo = mid + 1; else hi = mid; }
        s_hi = lo;
    }
    __syncthreads();
    int lo = s_lo, hi = s_hi;
    int m = threadIdx.x & 31;
    int r = threadIdx.x >> 5;   // 8 rows
    float s = 0.f;
    for (int n = lo + r; n < hi; n += 8) s += feats[(size_t)n * 32 + m];
    __shared__ float sm[8][32];
    sm[r][m] = s;
    __syncthreads();
    if (threadIdx.x == 0) {
        float cntf = (float)((hi - lo) > 0 ? (hi - lo) : 1);
        float tot = 0.f;
        for (int mm = 0; mm < 32; mm++) {
            float colsum = 0.f;
            for (int rr = 0; rr < 8; rr++) colsum += sm[rr][mm];
            tot += (colsum / cntf) * linW[mm];
        }
        out[g] = tot + linb[0];
    }
}

extern "C" void kernel_launch(void* const* d_in, const int* in_sizes, int n_in,
                              void* d_out, int out_size, void* d_ws, size_t ws_size,
                              hipStream_t stream) {
    const float* x    = (const float*)d_in[0];
    const float* pos  = (const float*)d_in[1];
    const int*   ei   = (const int*)d_in[2];
    const float* ea   = (const float*)d_in[3];
    const int*   bat  = (const int*)d_in[4];
    const float* W[24];
    for (int k = 0; k < 24; k++) W[k] = (const float*)d_in[5 + k];
    const float* linW = (const float*)d_in[29];
    const float* linb = (const float*)d_in[30];
    float* out = (float*)d_out;

    // workspace layout — ~106 MB (150 MB proven safe in round 1)
    char* p = (char*)d_ws;
    float4*  recs = (float4*)p;         p += (size_t)EE * 16;            // 25.6 MB
    __fp16*  u    = (__fp16*)p;         p += (size_t)NN * 132 * 2;       // 26.4 MB
    __fp16*  v    = (__fp16*)p;         p += (size_t)NN * 132 * 2;       // 26.4 MB
    float*   mi   = (float*)p;          p += (size_t)NN * 32 * 4;        // 12.8 MB
    float*   f    = (float*)p;          p += (size_t)NN * 32 * 4;        // 12.8 MB
    h2*      w2p1 = (h2*)p;             p += (size_t)(6  * 32) * 4;
    h2*      w2p2 = (h2*)p;             p += (size_t)(66 * 32) * 4;
    h2*      w2p3 = (h2*)p;             p += (size_t)(66 * 32) * 4;
    int*     cnt  = (int*)p;            p += (size_t)NN * 4;
    int*     rowptr = (int*)p;          p += (size_t)(NN + 4) * 4;
    int*     head = (int*)p;            p += (size_t)NN * 4;

    // ---- CSR build + weight prepack (once) ----
    (void)hipMemsetAsync(cnt, 0, (size_t)NN * 4, stream);
    k_hist<<<EE / 256, 256, 0, stream>>>(ei, cnt);
    k_scan<<<1, 1024, 0, stream>>>(cnt, rowptr, head);
    k_scatter<<<EE / 256, 256, 0, stream>>>(ei, ea, pos, head, recs);
    k_packw2<12> <<<1, 256, 0, stream>>>(W[2],  w2p1);
    k_packw2<132><<<(66 * 32 + 255) / 256, 256, 0, stream>>>(W[10], w2p2);
    k_packw2<132><<<(66 * 32 + 255) / 256, 256, 0, stream>>>(W[18], w2p3);

    // ---- layer 1: FI=2, DH=12 ----
    k_uv<2, 12><<<(NN * 12 + 255) / 256, 256, 0, stream>>>(x, W[0], u, v);
    (void)hipMemsetAsync(mi, 0, (size_t)NN * 32 * 4, stream);
    k_edge_agg<2, 12><<<EE / 256, 256, 0, stream>>>(u, v, recs, W[0], W[1], w2p1, W[3], mi);
    // node MLP 1 + u/v for layer 2 (eW1 = W[8])
    k_node<2, 132><<<NN / 4, 256, 0, stream>>>(x, mi, W[4], W[5], W[6], W[7], f, W[8], u, v);

    // ---- layer 2: FI=32, DH=132 ----
    (void)hipMemsetAsync(mi, 0, (size_t)NN * 32 * 4, stream);
    k_edge_agg<32, 132><<<EE / 256, 256, 0, stream>>>(u, v, recs, W[8], W[9], w2p2, W[11], mi);
    // node MLP 2 + u/v for layer 3 (eW1 = W[16])
    k_node<32, 132><<<NN / 4, 256, 0, stream>>>(f, mi, W[12], W[13], W[14], W[15], f, W[16], u, v);

    // ---- layer 3 ----
    (void)hipMemsetAsync(mi, 0, (size_t)NN * 32 * 4, stream);
    k_edge_agg<32, 132><<<EE / 256, 256, 0, stream>>>(u, v, recs, W[16], W[17], w2p3, W[19], mi);
    k_node<32, 0><<<NN / 4, 256, 0, stream>>>(f, mi, W[20], W[21], W[22], W[23], f, nullptr, nullptr, nullptr);

    k_pool<<<GG, 256, 0, stream>>>(f, bat, linW, linb, out);
}

// Round 9
// 1717.234 us; speedup vs baseline: 5.5282x; 1.1131x over previous
//
#include <hip/hip_runtime.h>
#include <hip/hip_bf16.h>

#define NN 100000
#define EE 1600000
#define GG 100

typedef __fp16 h2 __attribute__((ext_vector_type(2)));
typedef __fp16 h4v __attribute__((ext_vector_type(4)));
typedef float f4v __attribute__((ext_vector_type(4)));

#if __has_builtin(__builtin_amdgcn_fdot2)
#define FDOT2(a, b, c) __builtin_amdgcn_fdot2((a), (b), (c), false)
#else
__device__ __forceinline__ float FDOT2(h2 a, h2 b, float c) {
    return (float)a.x * (float)b.x + (float)a.y * (float)b.y + c;
}
#endif

#if __has_builtin(__builtin_amdgcn_mfma_f32_16x16x16f16)
#define MFMA16(a, b, c) __builtin_amdgcn_mfma_f32_16x16x16f16((a), (b), (c), 0, 0, 0)
#elif __has_builtin(__builtin_amdgcn_mfma_f32_16x16x16_f16)
#define MFMA16(a, b, c) __builtin_amdgcn_mfma_f32_16x16x16_f16((a), (b), (c), 0, 0, 0)
#else
__device__ __forceinline__ f4v mfma16_asm(h4v a, h4v b, f4v c) {
    asm volatile("v_mfma_f32_16x16x16_f16 %0, %1, %2, %0" : "+v"(c) : "v"(a), "v"(b));
    return c;
}
#define MFMA16(a, b, c) mfma16_asm((a), (b), (c))
#endif

__device__ __forceinline__ float silu_f(float x) {
    return x / (1.f + __expf(-x));
}

__device__ __forceinline__ float2 h2f2(unsigned int w) {
    h2 h = __builtin_bit_cast(h2, w);
    return make_float2((float)h.x, (float)h.y);
}

// ---------- CSR build (once per call; topology static across layers) ----------

__global__ void k_hist(const int* __restrict__ ei, int* __restrict__ cnt) {
    int e = blockIdx.x * 256 + threadIdx.x;
    if (e >= EE) return;
    atomicAdd(&cnt[ei[EE + e]], 1);   // dest node i
}

__global__ void __launch_bounds__(1024) k_scan(const int* __restrict__ cnt,
                                               int* __restrict__ rowptr,
                                               int* __restrict__ head) {
    __shared__ int sdata[1024];
    int t = threadIdx.x;
    const int chunk = (NN + 1023) / 1024;
    int lo = t * chunk; if (lo > NN) lo = NN;
    int hi = lo + chunk; if (hi > NN) hi = NN;
    int s = 0;
    for (int n = lo; n < hi; n++) s += cnt[n];
    sdata[t] = s;
    __syncthreads();
    for (int off = 1; off < 1024; off <<= 1) {
        int val = (t >= off) ? sdata[t - off] : 0;
        __syncthreads();
        sdata[t] += val;
        __syncthreads();
    }
    int run = sdata[t] - s;  // exclusive prefix of this chunk
    for (int n = lo; n < hi; n++) {
        rowptr[n] = run; head[n] = run; run += cnt[n];
    }
    if (t == 0) rowptr[NN] = EE;
}

// packed dest-sorted edge record: {j, i, ea, rd}
__global__ void k_scatter(const int* __restrict__ ei, const float* __restrict__ ea,
                          const float* __restrict__ pos, int* __restrict__ head,
                          float4* __restrict__ recs) {
    int e = blockIdx.x * 256 + threadIdx.x;
    if (e >= EE) return;
    int j = ei[e];
    int i = ei[EE + e];
    float dx = pos[2 * j] - pos[2 * i];
    float dy = pos[2 * j + 1] - pos[2 * i + 1];
    int p = atomicAdd(&head[i], 1);
    float4 r;
    r.x = __int_as_float(j);
    r.y = __int_as_float(i);
    r.z = ea[e];
    r.w = dx * dx + dy * dy;
    recs[p] = r;
}

// ---------- pack eW2 (DHx32 f32) into fp16 pairs (layer-1 dot2 path) ----------
template<int DH>
__global__ void k_packw2(const float* __restrict__ W2, h2* __restrict__ dst) {
    int idx = blockIdx.x * 256 + threadIdx.x;
    if (idx >= (DH / 2) * 32) return;
    int p = idx >> 5;
    int m = idx & 31;
    dst[idx] = __builtin_amdgcn_cvt_pkrtz(W2[(2 * p) * 32 + m], W2[(2 * p + 1) * 32 + m]);
}

// ---------- pack eW2 (132x32 f32) into MFMA B-fragments, K padded to 144 ----------
// B-frag (16x16x16_f16): lane l holds B[kbase + (l>>4)*4 + q][16*nt + (l&15)], q=0..3
// table[((s*2+nt)*64 + l)*4 + q]
__global__ void k_packBfrag(const float* __restrict__ W2, __fp16* __restrict__ dst) {
    int idx = blockIdx.x * 256 + threadIdx.x;   // [0, 9*2*64)
    if (idx >= 9 * 2 * 64) return;
    int l   = idx & 63;
    int snt = idx >> 6;
    int s   = snt >> 1;
    int nt  = snt & 1;
    int n   = (nt << 4) + (l & 15);
    int kb  = s * 16 + ((l >> 4) << 2);
    h4v val;
#pragma unroll
    for (int q = 0; q < 4; q++) {
        int k = kb + q;
        val[q] = (k < 132) ? (__fp16)W2[k * 32 + n] : (__fp16)0.f;
    }
    *(h4v*)(dst + (size_t)idx * 4) = val;
}

// ---------- per-node partial first-GEMM for LAYER 1 only ----------
template<int FI, int DH>
__global__ void k_uv(const float* __restrict__ feats, const float* __restrict__ W1,
                     __fp16* __restrict__ u, __fp16* __restrict__ v) {
    int idx = blockIdx.x * 256 + threadIdx.x;
    if (idx >= NN * DH) return;
    int n = idx / DH;
    int c = idx - n * DH;
    const float* f = feats + (size_t)n * FI;
    float su = 0.f, sv = 0.f;
#pragma unroll
    for (int k = 0; k < FI; k++) {
        float fk = f[k];
        su += fk * W1[k * DH + c];
        sv += fk * W1[(FI + k) * DH + c];
    }
    u[(size_t)n * DH + c] = (__fp16)su;
    v[(size_t)n * DH + c] = (__fp16)sv;
}

// ---------- layer-1 edge kernel (DH=12, dot2 path — proven) ----------
template<int FI, int DH>
__global__ void __launch_bounds__(256)
k_edge_agg(const __fp16* __restrict__ u, const __fp16* __restrict__ v,
           const float4* __restrict__ recs,
           const float* __restrict__ eW1, const float* __restrict__ eb1,
           const h2* __restrict__ w2pk, const float* __restrict__ eb2,
           float* __restrict__ mi) {
    constexpr int NC4 = DH / 4;
    constexpr int NP  = DH / 2;

    __shared__ __align__(16) float sA[DH], sB[DH], sb1[DH];
    __shared__ float sb2[32];
    __shared__ __align__(16) h2 sw2[NP * 32];

    for (int k = threadIdx.x; k < DH; k += 256) {
        sA[k]  = eW1[(2 * FI) * DH + k];
        sB[k]  = eW1[(2 * FI + 1) * DH + k];
        sb1[k] = eb1[k];
    }
    for (int k = threadIdx.x; k < NP * 32; k += 256) sw2[k] = w2pk[k];
    if (threadIdx.x < 32) sb2[threadIdx.x] = eb2[threadIdx.x];
    __syncthreads();

    int t = blockIdx.x * 256 + threadIdx.x;     // EE % 256 == 0
    float4 r = recs[t];
    int j = __float_as_int(r.x);
    int i = __float_as_int(r.y);
    float eav = r.z;
    float rdv = r.w;
    const uint2* up = (const uint2*)(u + (size_t)i * DH);
    const uint2* vp = (const uint2*)(v + (size_t)j * DH);

    h2 hreg[NP];
#pragma unroll
    for (int c4 = 0; c4 < NC4; c4++) {
        uint2 uu = up[c4];
        uint2 vv = vp[c4];
        float2 u01 = h2f2(uu.x), u23 = h2f2(uu.y);
        float2 v01 = h2f2(vv.x), v23 = h2f2(vv.y);
        float4 a  = *(const float4*)&sA[c4 * 4];
        float4 b  = *(const float4*)&sB[c4 * 4];
        float4 bb = *(const float4*)&sb1[c4 * 4];
        float t0 = silu_f(u01.x + v01.x + eav * a.x + rdv * b.x + bb.x);
        float t1 = silu_f(u01.y + v01.y + eav * a.y + rdv * b.y + bb.y);
        float t2 = silu_f(u23.x + v23.x + eav * a.z + rdv * b.z + bb.z);
        float t3 = silu_f(u23.y + v23.y + eav * a.w + rdv * b.w + bb.w);
        hreg[2 * c4]     = __builtin_amdgcn_cvt_pkrtz(t0, t1);
        hreg[2 * c4 + 1] = __builtin_amdgcn_cvt_pkrtz(t2, t3);
    }

    float acc[32];
#pragma unroll
    for (int m = 0; m < 32; m++) acc[m] = sb2[m];
#pragma unroll
    for (int mg = 0; mg < 8; mg++) {
#pragma unroll
        for (int p = 0; p < NP; p++) {
            uint4 W = *(const uint4*)(sw2 + p * 32 + mg * 4);
            acc[4 * mg + 0] = FDOT2(hreg[p], __builtin_bit_cast(h2, W.x), acc[4 * mg + 0]);
            acc[4 * mg + 1] = FDOT2(hreg[p], __builtin_bit_cast(h2, W.y), acc[4 * mg + 1]);
            acc[4 * mg + 2] = FDOT2(hreg[p], __builtin_bit_cast(h2, W.z), acc[4 * mg + 2]);
            acc[4 * mg + 3] = FDOT2(hreg[p], __builtin_bit_cast(h2, W.w), acc[4 * mg + 3]);
        }
    }
#pragma unroll
    for (int m = 0; m < 32; m++) acc[m] = silu_f(acc[m]);

    int lane = threadIdx.x & 63;
#pragma unroll
    for (int d = 1; d < 64; d <<= 1) {
        int oi = __shfl_down(i, d);
        bool take = (lane + d < 64) && (oi == i);
#pragma unroll
        for (int m = 0; m < 32; m++) {
            float ov = __shfl_down(acc[m], d);
            if (take) acc[m] += ov;
        }
    }
    int previ = __shfl_up(i, 1);
    int ilast = __shfl(i, 63);
    bool leader = (lane == 0) || (previ != i);
    if (leader) {
        float* row = mi + (size_t)i * 32;
        bool interior = (lane != 0) && (ilast != i);
        if (interior) {
            float4* row4 = (float4*)row;
#pragma unroll
            for (int q = 0; q < 8; q++)
                row4[q] = make_float4(acc[4 * q], acc[4 * q + 1], acc[4 * q + 2], acc[4 * q + 3]);
        } else {
#pragma unroll
            for (int m = 0; m < 32; m++) atomicAdd(row + m, acc[m]);
        }
    }
}

// ---------- layers 2/3 edge kernel: MFMA h1@W2 ----------
// per wave: 64 edges; h1[64][132->144] fp16 in LDS (row stride 148 f16, 8B aligned);
// 4 Mtiles x 2 Ntiles x 9 Ksteps of v_mfma_f32_16x16x16_f16; D->LDS [64][33] f32;
// per-half-wave run-scan aggregation (plain store interior runs, atomics at boundaries).
#define H1_STRIDE 148
#define WAVE_LDS_BYTES (64 * H1_STRIDE * 2)   // 18944
#define W_OFF 1728

__global__ void __launch_bounds__(256)
k_edge_mfma(const __fp16* __restrict__ u, const __fp16* __restrict__ v,
            const float4* __restrict__ recs,
            const float* __restrict__ eW1, const float* __restrict__ eb1,
            const __fp16* __restrict__ w2f, const float* __restrict__ eb2,
            float* __restrict__ mi) {
    constexpr int FI = 32, DH = 132, NC4 = 33, GK = 11, NGR = 3;

    __shared__ __align__(16) char smem[W_OFF + 4 * WAVE_LDS_BYTES];   // 77504 B
    float* sA  = (float*)smem;        // 132
    float* sB  = sA + 132;            // 132
    float* sb1 = sB + 132;            // 132
    float* sb2 = sb1 + 132;           // 32

    for (int k = threadIdx.x; k < DH; k += 256) {
        sA[k]  = eW1[(2 * FI) * DH + k];
        sB[k]  = eW1[(2 * FI + 1) * DH + k];
        sb1[k] = eb1[k];
    }
    if (threadIdx.x < 32) sb2[threadIdx.x] = eb2[threadIdx.x];
    __syncthreads();

    int wid  = threadIdx.x >> 6;
    int lane = threadIdx.x & 63;
    __fp16* h1w = (__fp16*)(smem + W_OFF + wid * WAVE_LDS_BYTES);

    int t = blockIdx.x * 256 + threadIdx.x;     // EE % 256 == 0
    float4 r = recs[t];
    int j = __float_as_int(r.x);
    int i = __float_as_int(r.y);
    float eav = r.z;
    float rdv = r.w;
    const uint2* up = (const uint2*)(u + (size_t)i * DH);
    const uint2* vp = (const uint2*)(v + (size_t)j * DH);

    // ---- h1 = silu(u_i + v_j + ea*A + rd*B + b1) ----
    h2 hreg[66];
#pragma unroll
    for (int g = 0; g < NGR; g++) {
        uint2 ub[GK], vb[GK];
#pragma unroll
        for (int k = 0; k < GK; k++) {
            ub[k] = up[g * GK + k];
            vb[k] = vp[g * GK + k];
        }
#pragma unroll
        for (int k = 0; k < GK; k++) {
            int c4 = g * GK + k;
            float2 u01 = h2f2(ub[k].x), u23 = h2f2(ub[k].y);
            float2 v01 = h2f2(vb[k].x), v23 = h2f2(vb[k].y);
            float4 a  = *(const float4*)&sA[c4 * 4];
            float4 b  = *(const float4*)&sB[c4 * 4];
            float4 bb = *(const float4*)&sb1[c4 * 4];
            float t0 = silu_f(u01.x + v01.x + eav * a.x + rdv * b.x + bb.x);
            float t1 = silu_f(u01.y + v01.y + eav * a.y + rdv * b.y + bb.y);
            float t2 = silu_f(u23.x + v23.x + eav * a.z + rdv * b.z + bb.z);
            float t3 = silu_f(u23.y + v23.y + eav * a.w + rdv * b.w + bb.w);
            hreg[2 * c4]     = __builtin_amdgcn_cvt_pkrtz(t0, t1);
            hreg[2 * c4 + 1] = __builtin_amdgcn_cvt_pkrtz(t2, t3);
        }
    }

    // ---- store h1 row to LDS (lane = edge), zero pad k=132..143 ----
    __fp16* hrow = h1w + lane * H1_STRIDE;
#pragma unroll
    for (int p = 0; p < 33; p++) {
        uint2 w;
        w.x = __builtin_bit_cast(unsigned int, hreg[2 * p]);
        w.y = __builtin_bit_cast(unsigned int, hreg[2 * p + 1]);
        *(uint2*)(hrow + 4 * p) = w;
    }
    *(uint2*)(hrow + 132) = make_uint2(0u, 0u);
    *(uint2*)(hrow + 136) = make_uint2(0u, 0u);
    *(uint2*)(hrow + 140) = make_uint2(0u, 0u);

    // ---- B-fragments from global (L1-resident 9.2 KB table) ----
    h4v bf[9][2];
#pragma unroll
    for (int s = 0; s < 9; s++) {
#pragma unroll
        for (int nt = 0; nt < 2; nt++)
            bf[s][nt] = *(const h4v*)(w2f + ((size_t)((s * 2 + nt) * 64 + lane)) * 4);
    }

    // ---- MFMA: D[64x32] = h1[64x144] @ W2[144x32] + b2 ----
    int c15 = lane & 15;
    int g4  = (lane >> 4) << 2;
    float b2lo = sb2[c15], b2hi = sb2[16 + c15];
    f4v acc[4][2];
#pragma unroll
    for (int mt = 0; mt < 4; mt++) {
        acc[mt][0] = (f4v){b2lo, b2lo, b2lo, b2lo};
        acc[mt][1] = (f4v){b2hi, b2hi, b2hi, b2hi};
    }
#pragma unroll
    for (int s = 0; s < 9; s++) {
#pragma unroll
        for (int mt = 0; mt < 4; mt++) {
            h4v a = *(const h4v*)(h1w + (16 * mt + c15) * H1_STRIDE + s * 16 + g4);
            acc[mt][0] = MFMA16(a, bf[s][0], acc[mt][0]);
            acc[mt][1] = MFMA16(a, bf[s][1], acc[mt][1]);
        }
    }

    // ---- D (+silu) and i to LDS (reuse h1 region; all A-frag reads complete via data dep) ----
    float* Db = (float*)h1w;            // [64][33] f32 = 8448 B
    int*   ib = (int*)(Db + 64 * 33);   // 64 ints
    ib[lane] = i;
#pragma unroll
    for (int mt = 0; mt < 4; mt++) {
#pragma unroll
        for (int q = 0; q < 4; q++) {
            int e = 16 * mt + g4 + q;   // D row = edge within wave
            Db[e * 33 + c15]      = silu_f(acc[mt][0][q]);
            Db[e * 33 + 16 + c15] = silu_f(acc[mt][1][q]);
        }
    }
    __syncthreads();

    // ---- aggregation: lane = (half, m-col); run-scan over 32 sorted edges ----
    int half = lane >> 5, c = lane & 31;
    int e0 = half << 5, e1 = e0 + 32;
    float racc = Db[e0 * 33 + c];
    int icur = ib[e0];
    int rstart = e0;
    for (int e = e0 + 1; e < e1; e++) {
        int ie = ib[e];
        float val = Db[e * 33 + c];
        if (ie != icur) {
            float* dst = mi + (size_t)icur * 32 + c;
            if (rstart > e0) *dst = racc;      // run fully interior to this half
            else atomicAdd(dst, racc);         // may extend into previous half/wave
            racc = val; icur = ie; rstart = e;
        } else {
            racc += val;
        }
    }
    atomicAdd(mi + (size_t)icur * 32 + c, racc);  // final run may continue past this half
}

// ---------- fused node MLP (+ next-layer u/v when NDH>0) ----------
template<int FI, int NDH>
__global__ void __launch_bounds__(256)
k_node(const float* __restrict__ feats, const float* __restrict__ mi,
       const float* __restrict__ nW1, const float* __restrict__ nb1,
       const float* __restrict__ nW2, const float* __restrict__ nb2,
       float* __restrict__ fout,
       const float* __restrict__ eW1n,
       __fp16* __restrict__ un, __fp16* __restrict__ vn) {
    __shared__ float g_lds[4][64];
    __shared__ float s_f[4][32];
    int ln = threadIdx.x >> 6;
    int c  = threadIdx.x & 63;
    int n  = blockIdx.x * 4 + ln;       // NN % 4 == 0
    float s = nb1[c];
    const float* f = feats + (size_t)n * FI;
#pragma unroll
    for (int k = 0; k < FI; k++) s += f[k] * nW1[k * 64 + c];
    const float* mrow = mi + (size_t)n * 32;
#pragma unroll
    for (int k = 0; k < 32; k++) s += mrow[k] * nW1[(FI + k) * 64 + c];
    g_lds[ln][c] = silu_f(s);
    __syncthreads();
    if (c < 32) {
        float o = nb2[c];
        const float* gr = g_lds[ln];
#pragma unroll
        for (int k = 0; k < 64; k++) o += gr[k] * nW2[k * 32 + c];
        fout[(size_t)n * 32 + c] = o;
        s_f[ln][c] = o;
    }
    if (NDH > 0) {
        __syncthreads();
        const float* fr = s_f[ln];
        for (int col = c; col < NDH; col += 64) {
            float su = 0.f, sv = 0.f;
#pragma unroll
            for (int k = 0; k < 32; k++) {
                float fk = fr[k];
                su += fk * eW1n[k * NDH + col];
                sv += fk * eW1n[(32 + k) * NDH + col];
            }
            un[(size_t)n * NDH + col] = (__fp16)su;
            vn[(size_t)n * NDH + col] = (__fp16)sv;
        }
    }
}

// ---------- per-graph mean pool + final linear ----------
__global__ void k_pool(const float* __restrict__ feats, const int* __restrict__ batch,
                       const float* __restrict__ linW, const float* __restrict__ linb,
                       float* __restrict__ out) {
    int g = blockIdx.x;
    __shared__ int s_lo, s_hi;
    if (threadIdx.x == 0) {
        int lo = 0, hi = NN;
        while (lo < hi) { int mid = (lo + hi) >> 1; if (batch[mid] < g) lo = mid + 1; else hi = mid; }
        s_lo = lo;
    }
    if (threadIdx.x == 1) {
        int lo = 0, hi = NN;
        while (lo < hi) { int mid = (lo + hi) >> 1; if (batch[mid] < g + 1) lo = mid + 1; else hi = mid; }
        s_hi = lo;
    }
    __syncthreads();
    int lo = s_lo, hi = s_hi;
    int m = threadIdx.x & 31;
    int r = threadIdx.x >> 5;
    float s = 0.f;
    for (int n = lo + r; n < hi; n += 8) s += feats[(size_t)n * 32 + m];
    __shared__ float sm[8][32];
    sm[r][m] = s;
    __syncthreads();
    if (threadIdx.x == 0) {
        float cntf = (float)((hi - lo) > 0 ? (hi - lo) : 1);
        float tot = 0.f;
        for (int mm = 0; mm < 32; mm++) {
            float colsum = 0.f;
            for (int rr = 0; rr < 8; rr++) colsum += sm[rr][mm];
            tot += (colsum / cntf) * linW[mm];
        }
        out[g] = tot + linb[0];
    }
}

extern "C" void kernel_launch(void* const* d_in, const int* in_sizes, int n_in,
                              void* d_out, int out_size, void* d_ws, size_t ws_size,
                              hipStream_t stream) {
    const float* x    = (const float*)d_in[0];
    const float* pos  = (const float*)d_in[1];
    const int*   ei   = (const int*)d_in[2];
    const float* ea   = (const float*)d_in[3];
    const int*   bat  = (const int*)d_in[4];
    const float* W[24];
    for (int k = 0; k < 24; k++) W[k] = (const float*)d_in[5 + k];
    const float* linW = (const float*)d_in[29];
    const float* linb = (const float*)d_in[30];
    float* out = (float*)d_out;

    // workspace layout — ~105 MB (150 MB proven safe)
    char* p = (char*)d_ws;
    float4*  recs = (float4*)p;         p += (size_t)EE * 16;            // 25.6 MB
    __fp16*  u    = (__fp16*)p;         p += (size_t)NN * 132 * 2;       // 26.4 MB
    __fp16*  v    = (__fp16*)p;         p += (size_t)NN * 132 * 2;       // 26.4 MB
    float*   mi   = (float*)p;          p += (size_t)NN * 32 * 4;        // 12.8 MB
    float*   f    = (float*)p;          p += (size_t)NN * 32 * 4;        // 12.8 MB
    h2*      w2p1 = (h2*)p;             p += (size_t)(6 * 32) * 4;       // layer-1 dot2 pack
    __fp16*  w2f2 = (__fp16*)p;         p += (size_t)(9 * 2 * 64 * 4) * 2;  // 9.2 KB B-frag table
    __fp16*  w2f3 = (__fp16*)p;         p += (size_t)(9 * 2 * 64 * 4) * 2;
    int*     cnt  = (int*)p;            p += (size_t)NN * 4;
    int*     rowptr = (int*)p;          p += (size_t)(NN + 4) * 4;
    int*     head = (int*)p;            p += (size_t)NN * 4;

    // ---- CSR build + weight prepack (once) ----
    (void)hipMemsetAsync(cnt, 0, (size_t)NN * 4, stream);
    k_hist<<<EE / 256, 256, 0, stream>>>(ei, cnt);
    k_scan<<<1, 1024, 0, stream>>>(cnt, rowptr, head);
    k_scatter<<<EE / 256, 256, 0, stream>>>(ei, ea, pos, head, recs);
    k_packw2<12><<<1, 256, 0, stream>>>(W[2], w2p1);
    k_packBfrag<<<5, 256, 0, stream>>>(W[10], w2f2);
    k_packBfrag<<<5, 256, 0, stream>>>(W[18], w2f3);

    // ---- layer 1: FI=2, DH=12 (dot2 path) ----
    k_uv<2, 12><<<(NN * 12 + 255) / 256, 256, 0, stream>>>(x, W[0], u, v);
    (void)hipMemsetAsync(mi, 0, (size_t)NN * 32 * 4, stream);
    k_edge_agg<2, 12><<<EE / 256, 256, 0, stream>>>(u, v, recs, W[0], W[1], w2p1, W[3], mi);
    k_node<2, 132><<<NN / 4, 256, 0, stream>>>(x, mi, W[4], W[5], W[6], W[7], f, W[8], u, v);

    // ---- layer 2: FI=32, DH=132 (MFMA path) ----
    (void)hipMemsetAsync(mi, 0, (size_t)NN * 32 * 4, stream);
    k_edge_mfma<<<EE / 256, 256, 0, stream>>>(u, v, recs, W[8], W[9], w2f2, W[11], mi);
    k_node<32, 132><<<NN / 4, 256, 0, stream>>>(f, mi, W[12], W[13], W[14], W[15], f, W[16], u, v);

    // ---- layer 3 ----
    (void)hipMemsetAsync(mi, 0, (size_t)NN * 32 * 4, stream);
    k_edge_mfma<<<EE / 256, 256, 0, stream>>>(u, v, recs, W[16], W[17], w2f3, W[19], mi);
    k_node<32, 0><<<NN / 4, 256, 0, stream>>>(f, mi, W[20], W[21], W[22], W[23], f, nullptr, nullptr, nullptr);

    k_pool<<<GG, 256, 0, stream>>>(f, bat, linW, linb, out);
}